// Round 1
// baseline (3155.633 us; speedup 1.0000x reference)
//
#include <hip/hip_runtime.h>
#include <hip/hip_bf16.h>

typedef unsigned int u32;
typedef unsigned long long u64;

#define NEGV (-1000000000.0f)
#define N_ANCH 261888
#define PRE_NMS 6000
#define POST_NMS 300

// ---------------- ws layout (bytes) ----------------
// scores_all : 0        .. 1047552   (261888 f32)
// boxes_all  : 0x100000 .. +4190208  (261888 float4)
// hist       : 0x500000 .. +16384    (4096 u32)
// cnts       : 0x504000 .. +32       ([0]=cand_cnt [1]=nvalid [2]=bucketB)
// cand       : 0x505000 .. +65536    (8192 u64)
// nms_scores : 0x520000 .. +24000
// nms_boxes  : 0x526000 .. +96000
// mat        : 0x540000 .. +4512000  (6000*94 u64)

__device__ __forceinline__ int bucket_of(float s) {
    if (!(s > 0.0f)) return 0;
    float t = s * 4096.0f;
    int b = (int)t;
    return b > 4095 ? 4095 : b;
}

// ================= K0: zero hist+counters =================
__global__ void kzero(u32* p) {
    for (int i = threadIdx.x; i < 4104; i += 1024) p[i] = 0u;
}

// ================= K1: fused conv3x3+relu + heads + decode =================
// block 256 threads; tile = 8 rows x 4 cols x all 256 oc
__global__ __launch_bounds__(256, 4) void conv_head(
    const float* __restrict__ in, const float* __restrict__ cw, const float* __restrict__ cb,
    const float* __restrict__ lw, const float* __restrict__ lb,
    const float* __restrict__ sw, const float* __restrict__ sb,
    float* __restrict__ scores_all, float4* __restrict__ boxes_all,
    int H, int W, int stride, int abase)
{
    __shared__ float smem[9536];              // 38144 B
    float* Wl = smem;                         // [36][256]
    float* Il = smem + 9216;                  // [4][10][8]
    const int tid = threadIdx.x;
    const int gx0 = blockIdx.x * 4;
    const int gy0 = blockIdx.y * 8;
    const int HW = H * W;

    float acc[8][4];
#pragma unroll
    for (int i = 0; i < 8; ++i)
#pragma unroll
        for (int j = 0; j < 4; ++j) acc[i][j] = 0.0f;

    for (int c = 0; c < 64; ++c) {            // ic chunks of 4
        __syncthreads();
        // stage weights: chunk = w[oc][4ic][9]; LDS layout [fidx(ic*9+k)][oc]
        {
            const float4* wq = (const float4*)cw;
#pragma unroll
            for (int j = 0; j < 9; ++j) {
                int q = tid + j * 256;        // 0..2303
                int oc = q / 9; int m = q - oc * 9;
                float4 v = wq[oc * 576 + c * 9 + m];
                int f = m * 4;
                Wl[(f + 0) * 256 + oc] = v.x;
                Wl[(f + 1) * 256 + oc] = v.y;
                Wl[(f + 2) * 256 + oc] = v.z;
                Wl[(f + 3) * 256 + oc] = v.w;
            }
        }
        // stage input tile 4ic x 10 x 6 (padded row stride 8)
        if (tid < 240) {
            int ic = tid / 60; int rr = tid - ic * 60;
            int row = rr / 6;  int col = rr - row * 6;
            int y = gy0 - 1 + row, x = gx0 - 1 + col;
            float v = 0.0f;
            if (y >= 0 && y < H && x >= 0 && x < W)
                v = in[(size_t)(c * 4 + ic) * HW + y * W + x];
            Il[ic * 80 + row * 8 + col] = v;
        }
        __syncthreads();
        // compute
#pragma unroll
        for (int ic = 0; ic < 4; ++ic) {
            float wk[9];
#pragma unroll
            for (int k = 0; k < 9; ++k) wk[k] = Wl[(ic * 9 + k) * 256 + tid];
#pragma unroll
            for (int iy = 0; iy < 10; ++iy) {
                float4 rv = *(const float4*)&Il[ic * 80 + iy * 8];
                float2 rv2 = *(const float2*)&Il[ic * 80 + iy * 8 + 4];
                float r[6] = {rv.x, rv.y, rv.z, rv.w, rv2.x, rv2.y};
#pragma unroll
                for (int dy = 0; dy < 3; ++dy) {
                    const int ty = iy - dy;
                    if (ty >= 0 && ty < 8) {
#pragma unroll
                        for (int tx = 0; tx < 4; ++tx)
#pragma unroll
                            for (int dx = 0; dx < 3; ++dx)
                                acc[ty][tx] += wk[dy * 3 + dx] * r[tx + dx];
                    }
                }
            }
        }
    }
    // bias + relu (h stays in registers, oc = tid)
    {
        float bv = cb[tid];
#pragma unroll
        for (int i = 0; i < 8; ++i)
#pragma unroll
            for (int j = 0; j < 4; ++j) acc[i][j] = fmaxf(acc[i][j] + bv, 0.0f);
    }
    __syncthreads();  // done reading Wl/Il
    // epilogue LDS: hl[16][260]@0, w1[18][260]@4160, ob[16][20]@8840, b1[18]@9160
    float* hl = smem;
    float* w1 = smem + 4160;
    float* ob = smem + 8840;
    float* b1 = smem + 9160;
#pragma unroll
    for (int j = 0; j < 18; ++j) {
        int e = tid + j * 256;                // 0..4607
        int o = e >> 8; int ch = e & 255;
        w1[o * 260 + ch] = (o < 12) ? lw[o * 256 + ch] : sw[(o - 12) * 256 + ch];
    }
    if (tid < 18) b1[tid] = (tid < 12) ? lb[tid] : sb[tid - 12];

#pragma unroll
    for (int half = 0; half < 2; ++half) {
        __syncthreads();
#pragma unroll
        for (int p = 0; p < 16; ++p) {
            int ty = half * 4 + (p >> 2), tx = p & 3;
            hl[p * 260 + tid] = acc[ty][tx];
        }
        __syncthreads();
        for (int it = tid; it < 288; it += 256) {
            int px = it / 18, o = it - px * 18;
            float a = b1[o];
            const float4* hv4 = (const float4*)&hl[px * 260];
            const float4* wv4 = (const float4*)&w1[o * 260];
#pragma unroll 8
            for (int cc = 0; cc < 64; ++cc) {
                float4 hv = hv4[cc], wv = wv4[cc];
                a += hv.x * wv.x; a += hv.y * wv.y; a += hv.z * wv.z; a += hv.w * wv.w;
            }
            ob[px * 20 + o] = a;
        }
        __syncthreads();
        if (tid < 48) {
            int px = tid / 3, a = tid - px * 3;
            int gy = gy0 + half * 4 + (px >> 2);
            int gx = gx0 + (px & 3);
            float dy = ob[px * 20 + a * 4 + 0];
            float dx = ob[px * 20 + a * 4 + 1];
            float dh = ob[px * 20 + a * 4 + 2];
            float dw = ob[px * 20 + a * 4 + 3];
            float s0 = ob[px * 20 + 12 + a * 2];
            float s1 = ob[px * 20 + 13 + a * 2];
            float mm = fmaxf(s0, s1);
            float e0 = expf(s0 - mm), e1 = expf(s1 - mm);
            float fg = e1 / (e0 + e1);
            float sqa = (a == 0) ? 0.70710678f : ((a == 1) ? 1.0f : 1.41421356f);
            float sqb = (a == 0) ? 1.41421356f : ((a == 1) ? 1.0f : 0.70710678f);
            float s8 = (float)(stride * 8);
            float hs = __fmul_rn(s8, sqa), wsz = __fmul_rn(s8, sqb);
            float g_y = (float)(gy * stride), g_x = (float)(gx * stride);
            // reproduce reference anchor corner/center round-trips exactly
            float a_y1 = __fsub_rn(g_y, __fmul_rn(hs, 0.5f));
            float a_y2 = __fadd_rn(g_y, __fmul_rn(hs, 0.5f));
            float a_x1 = __fsub_rn(g_x, __fmul_rn(wsz, 0.5f));
            float a_x2 = __fadd_rn(g_x, __fmul_rn(wsz, 0.5f));
            float ah = __fsub_rn(a_y2, a_y1), aw = __fsub_rn(a_x2, a_x1);
            float acy = __fadd_rn(a_y1, __fmul_rn(0.5f, ah));
            float acx = __fadd_rn(a_x1, __fmul_rn(0.5f, aw));
            float cy = __fadd_rn(__fmul_rn(dy, ah), acy);
            float cx = __fadd_rn(__fmul_rn(dx, aw), acx);
            float bh = __fmul_rn(expf(dh), ah);
            float bw = __fmul_rn(expf(dw), aw);
            float y1 = __fsub_rn(cy, __fmul_rn(0.5f, bh));
            float x1 = __fsub_rn(cx, __fmul_rn(0.5f, bw));
            float y2 = __fadd_rn(cy, __fmul_rn(0.5f, bh));
            float x2 = __fadd_rn(cx, __fmul_rn(0.5f, bw));
            y1 = fminf(fmaxf(y1, 0.0f), 1024.0f); x1 = fminf(fmaxf(x1, 0.0f), 1024.0f);
            y2 = fminf(fmaxf(y2, 0.0f), 1024.0f); x2 = fminf(fmaxf(x2, 0.0f), 1024.0f);
            float hh2 = __fsub_rn(y2, y1), ww2 = __fsub_rn(x2, x1);
            float sc = (hh2 >= 16.0f && ww2 >= 16.0f) ? fg : NEGV;
            int A = abase + (gy * W + gx) * 3 + a;
            scores_all[A] = sc;
            boxes_all[A] = make_float4(y1, x1, y2, x2);
        }
    }
}

// ================= K2: score histogram (4096 buckets) =================
__global__ void hist_k(const float* __restrict__ scores, u32* __restrict__ hist) {
    __shared__ u32 h[4096];
    int tid = threadIdx.x;
    for (int i = tid; i < 4096; i += 256) h[i] = 0u;
    __syncthreads();
    int gid = blockIdx.x * 256 + tid;
    int gs = gridDim.x * 256;
    for (int i = gid; i < N_ANCH; i += gs)
        atomicAdd(&h[bucket_of(scores[i])], 1u);
    __syncthreads();
    for (int i = tid; i < 4096; i += 256) if (h[i]) atomicAdd(&hist[i], h[i]);
}

// ================= K3: find cutoff bucket (single wave) =================
__global__ void select_bucket(const u32* __restrict__ hist, u32* __restrict__ cnts) {
    int lane = threadIdx.x;
    u32 S = 0;
    for (int c = 0; c < 64; ++c) {
        int bin = 4095 - (c * 64 + lane);
        u32 cnt = hist[bin];
        u32 cum = cnt;
        for (int off = 1; off < 64; off <<= 1) {
            u32 n = __shfl_up(cum, off, 64);
            if (lane >= off) cum += n;
        }
        u64 ball = __ballot(S + cum >= (u32)PRE_NMS);
        if (ball) {
            int l = __ffsll((long long)ball) - 1;
            if (lane == 0) cnts[2] = (u32)(4095 - (c * 64 + l));
            return;
        }
        S += __shfl(cum, 63, 64);
    }
    if (lane == 0) cnts[2] = 0u;
}

// ================= K4: compact candidates (bucket >= B) =================
__global__ void compact_k(const float* __restrict__ scores, u32* __restrict__ cnts,
                          u64* __restrict__ cand) {
    int B = (int)cnts[2];
    int gid = blockIdx.x * blockDim.x + threadIdx.x;
    int gs = gridDim.x * blockDim.x;
    for (int i = gid; i < N_ANCH; i += gs) {
        float s = scores[i];
        if (bucket_of(s) >= B) {
            u32 pos = atomicAdd(&cnts[0], 1u);
            if (pos < 8192u) {
                u32 u = __float_as_uint(s);
                u32 key = (u & 0x80000000u) ? ~u : (u | 0x80000000u);
                cand[pos] = ((u64)key << 32) | (u64)((u32)(~i));
            }
        }
    }
}

// ================= K5: bitonic sort (desc) + gather top-6000 =================
__global__ __launch_bounds__(1024) void sort_gather(
    const u64* __restrict__ cand, const u32* __restrict__ cnts,
    const float* __restrict__ sall, const float4* __restrict__ ball,
    float* __restrict__ nsc, float4* __restrict__ nbx, u32* __restrict__ nvalid)
{
    __shared__ u64 srt[8192];
    int tid = threadIdx.x;
    u32 total = cnts[0]; if (total > 8192u) total = 8192u;
    for (int i = tid; i < 8192; i += 1024) srt[i] = (i < (int)total) ? cand[i] : 0ULL;
    __syncthreads();
    for (int k = 2; k <= 8192; k <<= 1) {
        for (int j = k >> 1; j > 0; j >>= 1) {
            for (int i = tid; i < 8192; i += 1024) {
                int l = i ^ j;
                if (l > i) {
                    u64 a = srt[i], b = srt[l];
                    bool descRegion = (i & k) == 0;
                    if (descRegion ? (a < b) : (a > b)) { srt[i] = b; srt[l] = a; }
                }
            }
            __syncthreads();
        }
    }
    int local = 0;
    for (int i = tid; i < PRE_NMS; i += 1024) {
        u64 comp = srt[i];
        u32 idx = ~((u32)(comp & 0xFFFFFFFFULL));
        float s; float4 bx;
        if (idx < (u32)N_ANCH) { s = sall[idx]; bx = ball[idx]; }
        else { s = NEGV; bx = make_float4(0.f, 0.f, 0.f, 0.f); }
        nsc[i] = s;
        nbx[i] = bx;
        if (s > -5.0e8f) local++;
    }
    for (int off = 32; off > 0; off >>= 1) local += __shfl_down(local, off, 64);
    if ((tid & 63) == 0) atomicAdd(nvalid, (u32)local);
}

// ================= K6: IoU suppression bitmask matrix =================
__global__ void ioumat(const float4* __restrict__ bxs, u64* __restrict__ mat) {
    int i = blockIdx.x;
    int w = threadIdx.x;
    if (w >= 94) return;
    float4 bi = bxs[i];
    float a1 = (bi.z - bi.x) * (bi.w - bi.y);
    u64 bits = 0ULL;
    int j0 = w * 64;
    for (int b = 0; b < 64; ++b) {
        int j = j0 + b;
        if (j < PRE_NMS) {
            float4 bj = bxs[j];
            float ty = fmaxf(bi.x, bj.x), tx = fmaxf(bi.y, bj.y);
            float by = fminf(bi.z, bj.z), bx = fminf(bi.w, bj.w);
            float inter = fmaxf(by - ty, 0.0f) * fmaxf(bx - tx, 0.0f);
            float a2 = (bj.z - bj.x) * (bj.w - bj.y);
            float iou = inter / fmaxf(a1 + a2 - inter, 1e-9f);
            if (iou > 0.7f) bits |= (1ULL << b);
        }
    }
    mat[(size_t)i * 94 + w] = bits;
}

// ================= K7: greedy NMS over sorted candidates (single wave) =================
__global__ void greedy(const u64* __restrict__ mat, const float* __restrict__ nsc,
                       const float4* __restrict__ nbx, const u32* __restrict__ nvalid,
                       float* __restrict__ out) {
    int lane = threadIdx.x;
    __shared__ u64 remw[94];
    remw[lane] = 0ULL;
    if (lane < 30) remw[64 + lane] = 0ULL;
    __syncthreads();
    int nv = (int)*nvalid;
    if (nv > PRE_NMS) nv = PRE_NMS;
    int kept = 0;
    for (int i = 0; i < nv; ++i) {
        u64 wrd = remw[i >> 6];
        if (!((wrd >> (i & 63)) & 1ULL)) {
            const u64* row = mat + (size_t)i * 94;
            u64 m0 = row[lane];
            u64 m1 = (lane < 30) ? row[64 + lane] : 0ULL;
            remw[lane] |= m0;
            if (lane < 30) remw[64 + lane] |= m1;
            if (lane < 4) out[kept * 4 + lane] = ((const float*)nbx)[i * 4 + lane];
            ++kept;
            if (kept == POST_NMS) break;
        }
    }
    for (int idx = kept * 4 + lane; idx < POST_NMS * 4; idx += 64) out[idx] = 0.0f;
}

// ================= host =================
extern "C" void kernel_launch(void* const* d_in, const int* in_sizes, int n_in,
                              void* d_out, int out_size, void* d_ws, size_t ws_size,
                              hipStream_t stream) {
    const float* feats[5];
    for (int i = 0; i < 5; ++i) feats[i] = (const float*)d_in[i];
    const float* cw = (const float*)d_in[5];
    const float* cb = (const float*)d_in[6];
    const float* lw = (const float*)d_in[7];
    const float* lb = (const float*)d_in[8];
    const float* sw = (const float*)d_in[9];
    const float* sb = (const float*)d_in[10];
    float* out = (float*)d_out;
    char* ws = (char*)d_ws;

    float*  scores_all = (float*)(ws + 0);
    float4* boxes_all  = (float4*)(ws + 0x100000);
    u32*    hist       = (u32*)(ws + 0x500000);
    u32*    cnts       = (u32*)(ws + 0x504000);
    u64*    cand       = (u64*)(ws + 0x505000);
    float*  nsc        = (float*)(ws + 0x520000);
    float4* nbx        = (float4*)(ws + 0x526000);
    u64*    mat        = (u64*)(ws + 0x540000);

    hipLaunchKernelGGL(kzero, dim3(1), dim3(1024), 0, stream, hist);

    const int Hs[5] = {256, 128, 64, 32, 16};
    const int St[5] = {4, 8, 16, 32, 64};
    int base = 0;
    for (int l = 0; l < 5; ++l) {
        int H = Hs[l], W = Hs[l];
        dim3 g(W / 4, H / 8);
        hipLaunchKernelGGL(conv_head, g, dim3(256), 0, stream,
                           feats[l], cw, cb, lw, lb, sw, sb,
                           scores_all, boxes_all, H, W, St[l], base);
        base += H * W * 3;
    }
    hipLaunchKernelGGL(hist_k, dim3(64), dim3(256), 0, stream, scores_all, hist);
    hipLaunchKernelGGL(select_bucket, dim3(1), dim3(64), 0, stream, hist, cnts);
    hipLaunchKernelGGL(compact_k, dim3(512), dim3(256), 0, stream, scores_all, cnts, cand);
    hipLaunchKernelGGL(sort_gather, dim3(1), dim3(1024), 0, stream,
                       cand, cnts, scores_all, boxes_all, nsc, nbx, cnts + 1);
    hipLaunchKernelGGL(ioumat, dim3(PRE_NMS), dim3(128), 0, stream, nbx, mat);
    hipLaunchKernelGGL(greedy, dim3(1), dim3(64), 0, stream, mat, nsc, nbx, cnts + 1, out);
}

// Round 2
// 1999.032 us; speedup vs baseline: 1.5786x; 1.5786x over previous
//
#include <hip/hip_runtime.h>
#include <hip/hip_bf16.h>

typedef unsigned int u32;
typedef unsigned long long u64;
typedef float v2f __attribute__((ext_vector_type(2)));

#define NEGV (-1000000000.0f)
#define N_ANCH 261888
#define PRE_NMS 6000
#define POST_NMS 300

// ---------------- ws layout (bytes) ----------------
// scores_all : 0        (261888 f32)
// boxes_all  : 0x100000 (261888 float4)
// hist       : 0x500000 (4096 u32)
// cnts       : 0x504000 ([0]=cand_cnt [1]=nvalid [2]=bucketB)
// cand       : 0x505000 (8192 u64)
// nms_scores : 0x520000
// nms_boxes  : 0x526000
// mat        : 0x540000 (6000*94 u64 = 4.51MB)  } aliased: wt (2.36MB) lives here
// wt         : 0x540000 (64*36*256 f32)         } during conv, mat written after

__device__ __forceinline__ void gload_lds16(const float* g, float* l) {
    __builtin_amdgcn_global_load_lds((const __attribute__((address_space(1))) void*)g,
                                     (__attribute__((address_space(3))) void*)l, 16, 0, 0);
}

__device__ __forceinline__ int bucket_of(float s) {
    if (!(s > 0.0f)) return 0;
    float t = s * 4096.0f;
    int b = (int)t;
    return b > 4095 ? 4095 : b;
}

// ================= K0: zero hist+counters =================
__global__ void kzero(u32* p) {
    for (int i = threadIdx.x; i < 4104; i += 1024) p[i] = 0u;
}

// ================= K-1: weight transpose cw[oc][cf] -> wt[cf][oc] =================
__global__ void wtrans(const float* __restrict__ cw, float* __restrict__ wt) {
    int g = blockIdx.x * 256 + threadIdx.x;   // 589824 total
    int oc = g & 255; int cf = g >> 8;
    wt[g] = cw[oc * 2304 + cf];
}

// ================= K1: fused conv3x3+relu + heads + decode, ALL levels =================
// block 256 threads; tile = 8 rows x 8 cols x all 256 oc
__global__ __launch_bounds__(256, 4) void conv_head(
    const float* __restrict__ p2, const float* __restrict__ p3,
    const float* __restrict__ p4, const float* __restrict__ p5,
    const float* __restrict__ p6,
    const float* __restrict__ wt, const float* __restrict__ cb,
    const float* __restrict__ lw, const float* __restrict__ lb,
    const float* __restrict__ sw, const float* __restrict__ sb,
    float* __restrict__ scores_all, float4* __restrict__ boxes_all)
{
    __shared__ float smem[9696];              // 38784 B -> 4 blocks/CU
    float* Wl = smem;                         // [36][256]
    float* Il = smem + 9216;                  // [4][10][12]
    const int tid  = threadIdx.x;
    const int wv   = tid >> 6;                // wave id 0..3 (= ic within chunk)
    const int lane = tid & 63;

    int bid = blockIdx.x;
    const float* in; int W, lg, stride, abase, local;
    if (bid < 1024)      { in = p2; W = 256; lg = 5; stride = 4;  abase = 0;      local = bid; }
    else if (bid < 1280) { in = p3; W = 128; lg = 4; stride = 8;  abase = 196608; local = bid - 1024; }
    else if (bid < 1344) { in = p4; W = 64;  lg = 3; stride = 16; abase = 245760; local = bid - 1280; }
    else if (bid < 1360) { in = p5; W = 32;  lg = 2; stride = 32; abase = 258048; local = bid - 1344; }
    else                 { in = p6; W = 16;  lg = 1; stride = 64; abase = 261120; local = bid - 1360; }
    const int bx = local & ((1 << lg) - 1), by = local >> lg;
    const int gx0 = bx * 8, gy0 = by * 8;
    const int HW = W * W;

    v2f acc2[8][4];
#pragma unroll
    for (int i = 0; i < 8; ++i)
#pragma unroll
        for (int j = 0; j < 4; ++j) acc2[i][j] = (v2f){0.0f, 0.0f};

    // input-tile element assignment: wave wv stages ic=wv; lane handles e0=lane, e1=lane+64
    const int e1 = lane + 64;
    const int r0 = lane / 10, c0 = lane - r0 * 10;
    const int r1 = e1 / 10,   c1 = e1 - r1 * 10;
    const int y0g = gy0 - 1 + r0, x0g = gx0 - 1 + c0;
    const int y1g = gy0 - 1 + r1, x1g = gx0 - 1 + c1;
    const bool in0 = (y0g >= 0 && y0g < W && x0g >= 0 && x0g < W);
    const bool in1 = (lane < 36) && (y1g >= 0 && y1g < W && x1g >= 0 && x1g < W);
    const int iofs0 = y0g * W + x0g;
    const int iofs1 = y1g * W + x1g;

    for (int c = 0; c < 64; ++c) {
        __syncthreads();
        // ---- stage weights: 36 rows of 256, via global_load_lds (linear dest) ----
        const float* gsrc = wt + c * 9216 + wv * 256 + lane * 4;
        float* ldst = Wl + wv * 256;
#pragma unroll
        for (int k = 0; k < 9; ++k)
            gload_lds16(gsrc + k * 1024, ldst + k * 1024);
        // ---- stage input tile: ic=wv, 100 elems per wave ----
        const float* ibase = in + (size_t)(c * 4 + wv) * HW;
        float v0 = in0 ? ibase[iofs0] : 0.0f;
        Il[wv * 120 + r0 * 12 + c0] = v0;
        if (lane < 36) {
            float v1 = in1 ? ibase[iofs1] : 0.0f;
            Il[wv * 120 + r1 * 12 + c1] = v1;
        }
        __syncthreads();
        // ---- compute ----
#pragma unroll
        for (int ic = 0; ic < 4; ++ic) {
            float wk[9];
#pragma unroll
            for (int k = 0; k < 9; ++k) wk[k] = Wl[(ic * 9 + k) * 256 + tid];
#pragma unroll
            for (int iy = 0; iy < 10; ++iy) {
                const float* rb = &Il[ic * 120 + iy * 12];
                float4 ra = *(const float4*)rb;
                float4 rbq = *(const float4*)(rb + 4);
                float2 rc = *(const float2*)(rb + 8);
                float r[10] = {ra.x, ra.y, ra.z, ra.w, rbq.x, rbq.y, rbq.z, rbq.w, rc.x, rc.y};
#pragma unroll
                for (int dy = 0; dy < 3; ++dy) {
                    const int ty = iy - dy;
                    if (ty >= 0 && ty < 8) {
                        const float w0 = wk[dy * 3 + 0], w1 = wk[dy * 3 + 1], w2 = wk[dy * 3 + 2];
#pragma unroll
                        for (int t = 0; t < 4; ++t) {
                            acc2[ty][t] = __builtin_elementwise_fma((v2f){w0, w0}, (v2f){r[2*t+0], r[2*t+1]}, acc2[ty][t]);
                            acc2[ty][t] = __builtin_elementwise_fma((v2f){w1, w1}, (v2f){r[2*t+1], r[2*t+2]}, acc2[ty][t]);
                            acc2[ty][t] = __builtin_elementwise_fma((v2f){w2, w2}, (v2f){r[2*t+2], r[2*t+3]}, acc2[ty][t]);
                        }
                    }
                }
            }
        }
    }
    // bias + relu (oc = tid)
    {
        float bvv = cb[tid];
#pragma unroll
        for (int i = 0; i < 8; ++i)
#pragma unroll
            for (int j = 0; j < 4; ++j) {
                v2f t = acc2[i][j];
                t.x = fmaxf(t.x + bvv, 0.0f);
                t.y = fmaxf(t.y + bvv, 0.0f);
                acc2[i][j] = t;
            }
    }
    __syncthreads();   // all compute reads of Wl/Il done
    // epilogue LDS: hl[16][260]@0, w1[18][260]@4160, ob[16][20]@8840, b1[18]@9160
    float* hl = smem;
    float* w1 = smem + 4160;
    float* ob = smem + 8840;
    float* b1 = smem + 9160;
#pragma unroll
    for (int j = 0; j < 18; ++j) {
        int e = tid + j * 256;                // 0..4607
        int o = e >> 8; int ch = e & 255;
        w1[o * 260 + ch] = (o < 12) ? lw[o * 256 + ch] : sw[(o - 12) * 256 + ch];
    }
    if (tid < 18) b1[tid] = (tid < 12) ? lb[tid] : sb[tid - 12];

    for (int g = 0; g < 4; ++g) {             // 4 groups of 16 px (2 rows x 8 cols)
        __syncthreads();
#pragma unroll
        for (int p = 0; p < 16; ++p) {
            const int ty = (g << 1) + (p >> 3), tx = p & 7;
            hl[p * 260 + tid] = acc2[ty][tx >> 1][tx & 1];
        }
        __syncthreads();
        for (int it = tid; it < 288; it += 256) {
            int px = it / 18, o = it - px * 18;
            float a = b1[o];
            const float4* hv4 = (const float4*)&hl[px * 260];
            const float4* wv4 = (const float4*)&w1[o * 260];
#pragma unroll 8
            for (int cc = 0; cc < 64; ++cc) {
                float4 hv = hv4[cc], wq = wv4[cc];
                a += hv.x * wq.x; a += hv.y * wq.y; a += hv.z * wq.z; a += hv.w * wq.w;
            }
            ob[px * 20 + o] = a;
        }
        __syncthreads();
        if (tid < 48) {
            int px = tid / 3, a = tid - px * 3;
            int gy = gy0 + (g << 1) + (px >> 3);
            int gx = gx0 + (px & 7);
            float dy = ob[px * 20 + a * 4 + 0];
            float dx = ob[px * 20 + a * 4 + 1];
            float dh = ob[px * 20 + a * 4 + 2];
            float dw = ob[px * 20 + a * 4 + 3];
            float s0 = ob[px * 20 + 12 + a * 2];
            float s1 = ob[px * 20 + 13 + a * 2];
            float mm = fmaxf(s0, s1);
            float e0 = expf(s0 - mm), e1x = expf(s1 - mm);
            float fg = e1x / (e0 + e1x);
            float sqa = (a == 0) ? 0.70710678f : ((a == 1) ? 1.0f : 1.41421356f);
            float sqb = (a == 0) ? 1.41421356f : ((a == 1) ? 1.0f : 0.70710678f);
            float s8 = (float)(stride * 8);
            float hs = __fmul_rn(s8, sqa), wsz = __fmul_rn(s8, sqb);
            float g_y = (float)(gy * stride), g_x = (float)(gx * stride);
            float a_y1 = __fsub_rn(g_y, __fmul_rn(hs, 0.5f));
            float a_y2 = __fadd_rn(g_y, __fmul_rn(hs, 0.5f));
            float a_x1 = __fsub_rn(g_x, __fmul_rn(wsz, 0.5f));
            float a_x2 = __fadd_rn(g_x, __fmul_rn(wsz, 0.5f));
            float ah = __fsub_rn(a_y2, a_y1), aw = __fsub_rn(a_x2, a_x1);
            float acy = __fadd_rn(a_y1, __fmul_rn(0.5f, ah));
            float acx = __fadd_rn(a_x1, __fmul_rn(0.5f, aw));
            float cy = __fadd_rn(__fmul_rn(dy, ah), acy);
            float cx = __fadd_rn(__fmul_rn(dx, aw), acx);
            float bh = __fmul_rn(expf(dh), ah);
            float bw = __fmul_rn(expf(dw), aw);
            float y1 = __fsub_rn(cy, __fmul_rn(0.5f, bh));
            float x1 = __fsub_rn(cx, __fmul_rn(0.5f, bw));
            float y2 = __fadd_rn(cy, __fmul_rn(0.5f, bh));
            float x2 = __fadd_rn(cx, __fmul_rn(0.5f, bw));
            y1 = fminf(fmaxf(y1, 0.0f), 1024.0f); x1 = fminf(fmaxf(x1, 0.0f), 1024.0f);
            y2 = fminf(fmaxf(y2, 0.0f), 1024.0f); x2 = fminf(fmaxf(x2, 0.0f), 1024.0f);
            float hh2 = __fsub_rn(y2, y1), ww2 = __fsub_rn(x2, x1);
            float sc = (hh2 >= 16.0f && ww2 >= 16.0f) ? fg : NEGV;
            int A = abase + (gy * W + gx) * 3 + a;
            scores_all[A] = sc;
            boxes_all[A] = make_float4(y1, x1, y2, x2);
        }
    }
}

// ================= K2: score histogram (4096 buckets) =================
__global__ void hist_k(const float* __restrict__ scores, u32* __restrict__ hist) {
    __shared__ u32 h[4096];
    int tid = threadIdx.x;
    for (int i = tid; i < 4096; i += 256) h[i] = 0u;
    __syncthreads();
    int gid = blockIdx.x * 256 + tid;
    int gs = gridDim.x * 256;
    for (int i = gid; i < N_ANCH; i += gs)
        atomicAdd(&h[bucket_of(scores[i])], 1u);
    __syncthreads();
    for (int i = tid; i < 4096; i += 256) if (h[i]) atomicAdd(&hist[i], h[i]);
}

// ================= K3: find cutoff bucket (single wave) =================
__global__ void select_bucket(const u32* __restrict__ hist, u32* __restrict__ cnts) {
    int lane = threadIdx.x;
    u32 S = 0;
    for (int c = 0; c < 64; ++c) {
        int bin = 4095 - (c * 64 + lane);
        u32 cnt = hist[bin];
        u32 cum = cnt;
        for (int off = 1; off < 64; off <<= 1) {
            u32 n = __shfl_up(cum, off, 64);
            if (lane >= off) cum += n;
        }
        u64 ball = __ballot(S + cum >= (u32)PRE_NMS);
        if (ball) {
            int l = __ffsll((long long)ball) - 1;
            if (lane == 0) cnts[2] = (u32)(4095 - (c * 64 + l));
            return;
        }
        S += __shfl(cum, 63, 64);
    }
    if (lane == 0) cnts[2] = 0u;
}

// ================= K4: compact candidates (bucket >= B) =================
__global__ void compact_k(const float* __restrict__ scores, u32* __restrict__ cnts,
                          u64* __restrict__ cand) {
    int B = (int)cnts[2];
    int gid = blockIdx.x * blockDim.x + threadIdx.x;
    int gs = gridDim.x * blockDim.x;
    for (int i = gid; i < N_ANCH; i += gs) {
        float s = scores[i];
        if (bucket_of(s) >= B) {
            u32 pos = atomicAdd(&cnts[0], 1u);
            if (pos < 8192u) {
                u32 u = __float_as_uint(s);
                u32 key = (u & 0x80000000u) ? ~u : (u | 0x80000000u);
                cand[pos] = ((u64)key << 32) | (u64)((u32)(~i));
            }
        }
    }
}

// ================= K5: bitonic sort (desc) + gather top-6000 =================
__global__ __launch_bounds__(1024) void sort_gather(
    const u64* __restrict__ cand, const u32* __restrict__ cnts,
    const float* __restrict__ sall, const float4* __restrict__ ball,
    float* __restrict__ nsc, float4* __restrict__ nbx, u32* __restrict__ nvalid)
{
    __shared__ u64 srt[8192];
    int tid = threadIdx.x;
    u32 total = cnts[0]; if (total > 8192u) total = 8192u;
    for (int i = tid; i < 8192; i += 1024) srt[i] = (i < (int)total) ? cand[i] : 0ULL;
    __syncthreads();
    for (int k = 2; k <= 8192; k <<= 1) {
        for (int j = k >> 1; j > 0; j >>= 1) {
            for (int i = tid; i < 8192; i += 1024) {
                int l = i ^ j;
                if (l > i) {
                    u64 a = srt[i], b = srt[l];
                    bool descRegion = (i & k) == 0;
                    if (descRegion ? (a < b) : (a > b)) { srt[i] = b; srt[l] = a; }
                }
            }
            __syncthreads();
        }
    }
    int local = 0;
    for (int i = tid; i < PRE_NMS; i += 1024) {
        u64 comp = srt[i];
        u32 idx = ~((u32)(comp & 0xFFFFFFFFULL));
        float s; float4 bx;
        if (idx < (u32)N_ANCH) { s = sall[idx]; bx = ball[idx]; }
        else { s = NEGV; bx = make_float4(0.f, 0.f, 0.f, 0.f); }
        nsc[i] = s;
        nbx[i] = bx;
        if (s > -5.0e8f) local++;
    }
    for (int off = 32; off > 0; off >>= 1) local += __shfl_down(local, off, 64);
    if ((tid & 63) == 0) atomicAdd(nvalid, (u32)local);
}

// ================= K6: IoU suppression bitmask matrix =================
__global__ void ioumat(const float4* __restrict__ bxs, u64* __restrict__ mat) {
    int i = blockIdx.x;
    int w = threadIdx.x;
    if (w >= 94) return;
    float4 bi = bxs[i];
    float a1 = (bi.z - bi.x) * (bi.w - bi.y);
    u64 bits = 0ULL;
    int j0 = w * 64;
    for (int b = 0; b < 64; ++b) {
        int j = j0 + b;
        if (j < PRE_NMS) {
            float4 bj = bxs[j];
            float ty = fmaxf(bi.x, bj.x), tx = fmaxf(bi.y, bj.y);
            float by = fminf(bi.z, bj.z), bx = fminf(bi.w, bj.w);
            float inter = fmaxf(by - ty, 0.0f) * fmaxf(bx - tx, 0.0f);
            float a2 = (bj.z - bj.x) * (bj.w - bj.y);
            float iou = inter / fmaxf(a1 + a2 - inter, 1e-9f);
            if (iou > 0.7f) bits |= (1ULL << b);
        }
    }
    mat[(size_t)i * 94 + w] = bits;
}

// ================= K7: greedy NMS, suppression state in registers =================
__global__ void greedy(const u64* __restrict__ mat, const float* __restrict__ nbxf,
                       const u32* __restrict__ nvalid, float* __restrict__ out) {
    int lane = threadIdx.x;   // 64
    u64 rem0 = 0ULL, rem1 = 0ULL;   // lane owns words {lane, 64+lane}
    int nv = (int)*nvalid; if (nv > PRE_NMS) nv = PRE_NMS;
    int kept = 0;
    for (int widx = 0; widx * 64 < nv && kept < POST_NMS; ++widx) {
        u64 word = (widx < 64) ? __shfl(rem0, widx, 64) : __shfl(rem1, widx - 64, 64);
        int bmax = nv - widx * 64; if (bmax > 64) bmax = 64;
        for (int b = 0; b < bmax; ++b) {
            if (!((word >> b) & 1ULL)) {
                int i = widx * 64 + b;
                const u64* row = mat + (size_t)i * 94;
                rem0 |= row[lane];
                if (lane < 30) rem1 |= row[64 + lane];
                if (lane < 4) out[kept * 4 + lane] = nbxf[i * 4 + lane];
                ++kept;
                if (kept == POST_NMS) break;
                word = (widx < 64) ? __shfl(rem0, widx, 64) : __shfl(rem1, widx - 64, 64);
            }
        }
        if (kept == POST_NMS) break;
    }
    for (int idx = kept * 4 + lane; idx < POST_NMS * 4; idx += 64) out[idx] = 0.0f;
}

// ================= host =================
extern "C" void kernel_launch(void* const* d_in, const int* in_sizes, int n_in,
                              void* d_out, int out_size, void* d_ws, size_t ws_size,
                              hipStream_t stream) {
    const float* p2 = (const float*)d_in[0];
    const float* p3 = (const float*)d_in[1];
    const float* p4 = (const float*)d_in[2];
    const float* p5 = (const float*)d_in[3];
    const float* p6 = (const float*)d_in[4];
    const float* cw = (const float*)d_in[5];
    const float* cb = (const float*)d_in[6];
    const float* lw = (const float*)d_in[7];
    const float* lb = (const float*)d_in[8];
    const float* sw = (const float*)d_in[9];
    const float* sb = (const float*)d_in[10];
    float* out = (float*)d_out;
    char* ws = (char*)d_ws;

    float*  scores_all = (float*)(ws + 0);
    float4* boxes_all  = (float4*)(ws + 0x100000);
    u32*    hist       = (u32*)(ws + 0x500000);
    u32*    cnts       = (u32*)(ws + 0x504000);
    u64*    cand       = (u64*)(ws + 0x505000);
    float*  nsc        = (float*)(ws + 0x520000);
    float4* nbx        = (float4*)(ws + 0x526000);
    u64*    mat        = (u64*)(ws + 0x540000);
    float*  wt         = (float*)(ws + 0x540000);  // aliases mat (conv-phase only)

    hipLaunchKernelGGL(kzero, dim3(1), dim3(1024), 0, stream, hist);
    hipLaunchKernelGGL(wtrans, dim3(2304), dim3(256), 0, stream, cw, wt);
    hipLaunchKernelGGL(conv_head, dim3(1364), dim3(256), 0, stream,
                       p2, p3, p4, p5, p6, wt, cb, lw, lb, sw, sb,
                       scores_all, boxes_all);
    hipLaunchKernelGGL(hist_k, dim3(64), dim3(256), 0, stream, scores_all, hist);
    hipLaunchKernelGGL(select_bucket, dim3(1), dim3(64), 0, stream, hist, cnts);
    hipLaunchKernelGGL(compact_k, dim3(512), dim3(256), 0, stream, scores_all, cnts, cand);
    hipLaunchKernelGGL(sort_gather, dim3(1), dim3(1024), 0, stream,
                       cand, cnts, scores_all, boxes_all, nsc, nbx, cnts + 1);
    hipLaunchKernelGGL(ioumat, dim3(PRE_NMS), dim3(128), 0, stream, nbx, mat);
    hipLaunchKernelGGL(greedy, dim3(1), dim3(64), 0, stream, mat, (const float*)nbx, cnts + 1, out);
}